// Round 3
// baseline (241.169 us; speedup 1.0000x reference)
//
#include <hip/hip_runtime.h>
#include <hip/hip_bf16.h>

#define N_   16
#define CI_  256
#define CO_  256
#define D_   4096
#define DO_  8192
#define KTOT 768            // 3 taps (j outer) x 256 ci
#define XTROWS 4098         // 4096 t + 1 zero pad row each side
#define WT_ELEMS (512 * KTOT)
#define XT_ELEMS ((size_t)N_ * XTROWS * 256)

typedef short frag8 __attribute__((ext_vector_type(8)));   // 8 bf16 (4 VGPR)
typedef float facc4 __attribute__((ext_vector_type(4)));   // 4 f32 acc

static __device__ __forceinline__ unsigned short f2bf(float f) {
    union { __hip_bfloat16 h; unsigned short u; } cv;
    cv.h = __float2bfloat16(f);
    return cv.u;
}

static __device__ __forceinline__ unsigned int pack2(float lo, float hi) {
    return (unsigned int)f2bf(lo) | ((unsigned int)f2bf(hi) << 16);
}

static __device__ __forceinline__ void async16(unsigned short* lds, const unsigned short* g) {
    __builtin_amdgcn_global_load_lds(
        (const __attribute__((address_space(1))) unsigned int*)g,
        (__attribute__((address_space(3))) unsigned int*)lds, 16, 0, 0);
}

// opaque LDS read: no "memory" clobber -> compiler has no alias edge to the
// in-flight global_load_lds writes, so it cannot insert vmcnt(0) drains.
#define DSREAD(dst, a, litoff) \
    asm volatile("ds_read_b128 %0, %1 offset:" litoff : "=&v"(dst) : "v"(a))

// ---------------- prep 1: effective bf16 weights -------------------------
// Wt[m = co*2+phase][k = j*256 + ci]; j=0 -> x[t-1], j=1 -> x[t], j=2 -> x[t+1]
__global__ __launch_bounds__(256) void prep_wt(const float* __restrict__ w,
                                               unsigned short* __restrict__ Wt) {
    const int ci = threadIdx.x;
    const int co = blockIdx.x;
    const float* wp = w + ((size_t)co * CI_ + ci) * 3;
    const float w0 = wp[0], w1 = wp[1], w2 = wp[2];
    const float e0 = 0.25f * w1 + 0.75f * w0;
    const float e1 = 0.75f * w2 + 0.75f * w1 + 0.25f * w0;
    const float e2 = 0.25f * w2;
    const float o0 = 0.25f * w0;
    const float o1 = 0.25f * w2 + 0.75f * w1 + 0.75f * w0;
    const float o2 = 0.75f * w2 + 0.25f * w1;
    unsigned short* pe = Wt + (size_t)(co * 2 + 0) * KTOT;
    unsigned short* po = Wt + (size_t)(co * 2 + 1) * KTOT;
    pe[0 * 256 + ci] = f2bf(e0); pe[1 * 256 + ci] = f2bf(e1); pe[2 * 256 + ci] = f2bf(e2);
    po[0 * 256 + ci] = f2bf(o0); po[1 * 256 + ci] = f2bf(o1); po[2 * 256 + ci] = f2bf(o2);
}

// ---------------- prep 2: x [n][ci][t] f32 -> x_t [n][t+1][ci] bf16 ------
__global__ __launch_bounds__(256) void prep_xt2(const float* __restrict__ x,
                                                unsigned short* __restrict__ xt) {
    __shared__ unsigned int Lp[32][133];   // [t][ci_pair], pitch 133
    const int tid = threadIdx.x;
    const int t0  = blockIdx.x * 32;
    const int n   = blockIdx.y;
    const float* xn = x + (size_t)n * CI_ * D_;
    unsigned short* slab = xt + (size_t)n * XTROWS * 256;

    // zero pad rows (t = -1 and t = 4096), each 512B = 128 u32
    if (t0 == 0 && tid < 128)       ((unsigned int*)slab)[tid] = 0u;
    if (t0 == D_ - 32 && tid < 128) ((unsigned int*)(slab + (size_t)(XTROWS - 1) * 256))[tid] = 0u;

    const int cp_l  = tid >> 3;        // 0..31  (ci-pair within pass)
    const int t_off = (tid & 7) * 4;   // 0,4,...,28

    #pragma unroll
    for (int p = 0; p < 4; ++p) {
        const int ci0 = p * 64 + cp_l * 2;
        float4 a = *(const float4*)(xn + (size_t)ci0 * D_ + t0 + t_off);
        float4 b = *(const float4*)(xn + (size_t)(ci0 + 1) * D_ + t0 + t_off);
        const int cp = p * 32 + cp_l;
        Lp[t_off + 0][cp] = pack2(a.x, b.x);
        Lp[t_off + 1][cp] = pack2(a.y, b.y);
        Lp[t_off + 2][cp] = pack2(a.z, b.z);
        Lp[t_off + 3][cp] = pack2(a.w, b.w);
    }
    __syncthreads();

    // write: 4 iters x 8 rows; 32 lanes x 16B = one full 512B t-row
    #pragma unroll
    for (int it = 0; it < 4; ++it) {
        const int row = it * 8 + (tid >> 5);
        const int c4  = (tid & 31) * 4;           // u32 index within row
        uint4 v;
        v.x = Lp[row][c4 + 0];
        v.y = Lp[row][c4 + 1];
        v.z = Lp[row][c4 + 2];
        v.w = Lp[row][c4 + 3];
        *(uint4*)(slab + (size_t)(1 + t0 + row) * 256 + c4 * 2) = v;
    }
}

// ---------------- main: 256m x 128t tile bf16 MFMA GEMM + fused epilogue --
// C[m][t] = sum_k Wt[m][k] * B[k][t],  B[k][t] = xt[n][t+1][k-part]
// Geometry change (round 3): wave tile 128m x 64t (acc 8x4) -> +33% FLOPs per
// LDS-read byte, 2x FLOPs per barrier/vmcnt, A-panel staged half as often.
// Schedule: 3-buffer 2-deep counted-vmcnt pipeline (verified rounds 1-2).
__global__ __launch_bounds__(256) void gemm_upfir(
    const unsigned short* __restrict__ Wt, const unsigned short* __restrict__ xt,
    const float* __restrict__ bias, float* __restrict__ out)
{
    __shared__ __align__(16) unsigned short As[3][256 * 32];   // 3 x 16 KB
    __shared__ __align__(16) unsigned short Bs[3][128 * 32];   // 3 x  8 KB

    const int tid  = threadIdx.x;
    const int lane = tid & 63;
    const int wid  = tid >> 6;
    const int quad = lane >> 4;
    const int l16  = lane & 15;

    const int bt0 = blockIdx.x * 128;   // t tile
    const int bm0 = blockIdx.y * 256;   // m tile (m = co*2+phase)
    const int n   = blockIdx.z;

    // staging: per K-step 24 KB = 24 x 1KB global_load_lds; 6 per wave
    // (4 A-chunks + 2 B-chunks). LDS slot holds global chunk slot ^ ((srow>>1)&3).
    const int srow = lane >> 2;        // 0..15 row within 16-row chunk
    const int slot = lane & 3;
    const int cg   = slot ^ ((srow >> 1) & 3);
    const unsigned short* gA = Wt + (size_t)(bm0 + wid * 64 + srow) * KTOT + cg * 8;
    const unsigned short* gB = xt + (size_t)n * XTROWS * 256
                                  + (size_t)(bt0 + wid * 32 + srow) * 256 + cg * 8;
    const int ldsA = (wid * 64) * 32;  // ushort offset of this wave's A chunk 0
    const int ldsB = (wid * 32) * 32;  // ushort offset of this wave's B chunk 0

    const int swz = quad ^ ((l16 >> 1) & 3);
    const int wm  = (wid & 1) * 128;   // wave m-range (128 rows)
    const int wt  = (wid >> 1) * 64;   // wave t-range (64 cols)

    // per-lane LDS byte addresses; frag a/b adds literal a*1024 (16 rows x 64B);
    // buffer bc adds bc*16384 (A) / bc*8192 (B)
    const unsigned baseA = (unsigned)(size_t)&As[0][0];
    const unsigned baseB = (unsigned)(size_t)&Bs[0][0];
    const unsigned plA = baseA + (unsigned)(((wm + l16) * 32 + swz * 8) * 2);
    const unsigned plB = baseB + (unsigned)(((wt + l16) * 32 + swz * 8) * 2);

    facc4 acc[8][4] = {};

    // stage one K-step (6 loads/wave) into buffer b
    #define STAGE(b, s)                                                          \
        do {                                                                     \
            unsigned short* da = &As[b][0] + ldsA;                               \
            unsigned short* db = &Bs[b][0] + ldsB;                               \
            async16(da + 0 * 512, gA + (size_t)0 * 16 * KTOT + (s) * 32);        \
            async16(da + 1 * 512, gA + (size_t)1 * 16 * KTOT + (s) * 32);        \
            async16(da + 2 * 512, gA + (size_t)2 * 16 * KTOT + (s) * 32);        \
            async16(da + 3 * 512, gA + (size_t)3 * 16 * KTOT + (s) * 32);        \
            async16(db + 0 * 512, gB + (size_t)0 * 16 * 256 + (s) * 32);         \
            async16(db + 1 * 512, gB + (size_t)1 * 16 * 256 + (s) * 32);         \
        } while (0)

    // prologue: stage tiles 0 and 1 (12 loads/wave in flight)
    STAGE(0, 0);
    STAGE(1, 1);

    // steady state at loop top: stage(s), stage(s+1) outstanding (12 loads).
    // vmcnt(6) drains stage(s); barrier => buf[s%3] ready everywhere AND all
    // waves finished reads of buf[(s-1)%3] => buf[(s+2)%3] free to restage.
    #pragma unroll
    for (int s = 0; s < 24; ++s) {
        const int bc = s % 3;
        const int bn = (s + 2) % 3;
        if (s < 23) asm volatile("s_waitcnt vmcnt(6)" ::: "memory");
        else        asm volatile("s_waitcnt vmcnt(0)" ::: "memory");
        __builtin_amdgcn_s_barrier();

        // fragment reads: B first, then A (MFMA group a waits lgkmcnt(7-a))
        const unsigned ab = plA + (unsigned)(bc * 16384);
        const unsigned bb = plB + (unsigned)(bc * 8192);
        frag8 af[8], bfr[4];
        DSREAD(bfr[0], bb, "0");
        DSREAD(bfr[1], bb, "1024");
        DSREAD(bfr[2], bb, "2048");
        DSREAD(bfr[3], bb, "3072");
        DSREAD(af[0],  ab, "0");
        DSREAD(af[1],  ab, "1024");
        DSREAD(af[2],  ab, "2048");
        DSREAD(af[3],  ab, "3072");
        DSREAD(af[4],  ab, "4096");
        DSREAD(af[5],  ab, "5120");
        DSREAD(af[6],  ab, "6144");
        DSREAD(af[7],  ab, "7168");

        // stage s+2 while the ds_reads are in flight
        if (s + 2 < 24) STAGE(bn, s + 2);

        __builtin_amdgcn_s_setprio(1);
        #define MFMA_GROUP(a, lit)                                               \
            asm volatile("s_waitcnt lgkmcnt(" lit ")" ::: "memory");             \
            __builtin_amdgcn_sched_barrier(0);                                   \
            acc[a][0] = __builtin_amdgcn_mfma_f32_16x16x32_bf16(af[a], bfr[0], acc[a][0], 0, 0, 0); \
            acc[a][1] = __builtin_amdgcn_mfma_f32_16x16x32_bf16(af[a], bfr[1], acc[a][1], 0, 0, 0); \
            acc[a][2] = __builtin_amdgcn_mfma_f32_16x16x32_bf16(af[a], bfr[2], acc[a][2], 0, 0, 0); \
            acc[a][3] = __builtin_amdgcn_mfma_f32_16x16x32_bf16(af[a], bfr[3], acc[a][3], 0, 0, 0);
        MFMA_GROUP(0, "7")
        MFMA_GROUP(1, "6")
        MFMA_GROUP(2, "5")
        MFMA_GROUP(3, "4")
        MFMA_GROUP(4, "3")
        MFMA_GROUP(5, "2")
        MFMA_GROUP(6, "1")
        MFMA_GROUP(7, "0")
        #undef MFMA_GROUP
        __builtin_amdgcn_s_setprio(0);
    }
    #undef STAGE

    // epilogue: D row = quad*4+reg (= m), col = l16 (= t); regs span 2 co x 2 phase
    #pragma unroll
    for (int a = 0; a < 8; ++a) {
        int m0  = bm0 + wm + a * 16 + quad * 4;
        int co0 = m0 >> 1;
        float b0 = bias[co0];
        float b1 = bias[co0 + 1];
        #pragma unroll
        for (int b = 0; b < 4; ++b) {
            int t = bt0 + wt + b * 16 + l16;
            facc4 v = acc[a][b];
            float* p0 = out + ((size_t)(n * CO_ + co0)) * DO_ + 2 * t;
            float* p1 = p0 + DO_;
            *(float2*)p0 = make_float2(v.x + b0, v.y + b0);
            *(float2*)p1 = make_float2(v.z + b1, v.w + b1);
        }
    }
}

// ---------------- fallback (round-1 verified kernel) ---------------------
__global__ __launch_bounds__(256) void upconv_fir_f32(
    const float* __restrict__ x, const float* __restrict__ w,
    const float* __restrict__ bias, float* __restrict__ out)
{
    __shared__ float ws[CI_][4];
    const int tid = threadIdx.x;
    const int co  = blockIdx.y;
    const int n   = blockIdx.z;
    {
        const float* wc = w + (size_t)co * CI_ * 3;
        ws[tid][0] = wc[tid * 3 + 0];
        ws[tid][1] = wc[tid * 3 + 1];
        ws[tid][2] = wc[tid * 3 + 2];
        ws[tid][3] = 0.f;
    }
    __syncthreads();
    const int t0 = (blockIdx.x * 256 + tid) * 8;
    const float* xn = x + (size_t)n * CI_ * D_;
    float s[10], g[9];
    #pragma unroll
    for (int k = 0; k < 10; ++k) s[k] = 0.f;
    #pragma unroll
    for (int k = 0; k < 9; ++k) g[k] = 0.f;
    #pragma unroll 2
    for (int ci = 0; ci < CI_; ++ci) {
        const float* xr = xn + ci * D_;
        float4 va = *(const float4*)(xr + t0);
        float4 vb = *(const float4*)(xr + t0 + 4);
        float  xm = (t0 > 0)      ? xr[t0 - 1] : 0.f;
        float  xp = (t0 + 8 < D_) ? xr[t0 + 8] : 0.f;
        float4 wv = *(const float4*)(&ws[ci][0]);
        const float w0 = wv.x, w1 = wv.y, w2 = wv.z;
        float xa[10];
        xa[0] = xm; xa[1] = va.x; xa[2] = va.y; xa[3] = va.z; xa[4] = va.w;
        xa[5] = vb.x; xa[6] = vb.y; xa[7] = vb.z; xa[8] = vb.w; xa[9] = xp;
        #pragma unroll
        for (int k = 0; k < 10; ++k) s[k] += w1 * xa[k];
        #pragma unroll
        for (int k = 0; k < 9; ++k)  g[k] += w0 * xa[k] + w2 * xa[k + 1];
    }
    const float b = bias[co];
    float o16[16];
    #pragma unroll
    for (int tt = 0; tt < 8; ++tt) {
        o16[2 * tt]     = 0.25f * (s[tt] + g[tt + 1]) + 0.75f * (g[tt] + s[tt + 1]) + b;
        o16[2 * tt + 1] = 0.25f * (g[tt] + s[tt + 2]) + 0.75f * (s[tt + 1] + g[tt + 1]) + b;
    }
    float* ob = out + ((size_t)n * CO_ + co) * DO_ + 2 * t0;
    *(float4*)(ob + 0)  = make_float4(o16[0],  o16[1],  o16[2],  o16[3]);
    *(float4*)(ob + 4)  = make_float4(o16[4],  o16[5],  o16[6],  o16[7]);
    *(float4*)(ob + 8)  = make_float4(o16[8],  o16[9],  o16[10], o16[11]);
    *(float4*)(ob + 12) = make_float4(o16[12], o16[13], o16[14], o16[15]);
}

extern "C" void kernel_launch(void* const* d_in, const int* in_sizes, int n_in,
                              void* d_out, int out_size, void* d_ws, size_t ws_size,
                              hipStream_t stream) {
    const float* x  = (const float*)d_in[0];
    const float* w  = (const float*)d_in[1];
    const float* b  = (const float*)d_in[2];
    float* out      = (float*)d_out;

    const size_t need = (size_t)WT_ELEMS * 2 + XT_ELEMS * 2;
    if (ws_size >= need) {
        unsigned short* Wt = (unsigned short*)d_ws;
        unsigned short* xt = Wt + WT_ELEMS;
        prep_wt<<<dim3(CO_), 256, 0, stream>>>(w, Wt);
        prep_xt2<<<dim3(D_ / 32, N_), 256, 0, stream>>>(x, xt);
        gemm_upfir<<<dim3(D_ / 128, 2, N_), 256, 0, stream>>>(Wt, xt, b, out);
    } else {
        upconv_fir_f32<<<dim3(2, CO_, N_), 256, 0, stream>>>(x, w, b, out);
    }
}

// Round 4
// 236.140 us; speedup vs baseline: 1.0213x; 1.0213x over previous
//
#include <hip/hip_runtime.h>
#include <hip/hip_bf16.h>

#define N_   16
#define CI_  256
#define CO_  256
#define D_   4096
#define DO_  8192
#define KTOT 768            // 3 taps (j outer) x 256 ci
#define XTROWS 4098         // 4096 t + 1 zero pad row each side
#define WT_ELEMS (512 * KTOT)
#define XT_ELEMS ((size_t)N_ * XTROWS * 256)

typedef short frag8 __attribute__((ext_vector_type(8)));   // 8 bf16 (4 VGPR)
typedef float facc4 __attribute__((ext_vector_type(4)));   // 4 f32 acc

static __device__ __forceinline__ unsigned short f2bf(float f) {
    union { __hip_bfloat16 h; unsigned short u; } cv;
    cv.h = __float2bfloat16(f);
    return cv.u;
}

static __device__ __forceinline__ unsigned int pack2(float lo, float hi) {
    return (unsigned int)f2bf(lo) | ((unsigned int)f2bf(hi) << 16);
}

static __device__ __forceinline__ void async16(unsigned short* lds, const unsigned short* g) {
    __builtin_amdgcn_global_load_lds(
        (const __attribute__((address_space(1))) unsigned int*)g,
        (__attribute__((address_space(3))) unsigned int*)lds, 16, 0, 0);
}

// opaque LDS read: no "memory" clobber -> compiler has no alias edge to the
// in-flight global_load_lds writes, so it cannot insert vmcnt(0) drains.
#define DSR_(dst, addr, litstr) \
    asm volatile("ds_read_b128 %0, %1 offset:" litstr : "=&v"(dst) : "v"(addr))

// ---------------- prep 1: effective bf16 weights -------------------------
// Wt[m = co*2+phase][k = j*256 + ci]; j=0 -> x[t-1], j=1 -> x[t], j=2 -> x[t+1]
__global__ __launch_bounds__(256) void prep_wt(const float* __restrict__ w,
                                               unsigned short* __restrict__ Wt) {
    const int ci = threadIdx.x;
    const int co = blockIdx.x;
    const float* wp = w + ((size_t)co * CI_ + ci) * 3;
    const float w0 = wp[0], w1 = wp[1], w2 = wp[2];
    const float e0 = 0.25f * w1 + 0.75f * w0;
    const float e1 = 0.75f * w2 + 0.75f * w1 + 0.25f * w0;
    const float e2 = 0.25f * w2;
    const float o0 = 0.25f * w0;
    const float o1 = 0.25f * w2 + 0.75f * w1 + 0.75f * w0;
    const float o2 = 0.75f * w2 + 0.25f * w1;
    unsigned short* pe = Wt + (size_t)(co * 2 + 0) * KTOT;
    unsigned short* po = Wt + (size_t)(co * 2 + 1) * KTOT;
    pe[0 * 256 + ci] = f2bf(e0); pe[1 * 256 + ci] = f2bf(e1); pe[2 * 256 + ci] = f2bf(e2);
    po[0 * 256 + ci] = f2bf(o0); po[1 * 256 + ci] = f2bf(o1); po[2 * 256 + ci] = f2bf(o2);
}

// ---------------- prep 2: x [n][ci][t] f32 -> x_t [n][t+1][ci] bf16 ------
__global__ __launch_bounds__(256) void prep_xt2(const float* __restrict__ x,
                                                unsigned short* __restrict__ xt) {
    __shared__ unsigned int Lp[32][133];   // [t][ci_pair], pitch 133
    const int tid = threadIdx.x;
    const int t0  = blockIdx.x * 32;
    const int n   = blockIdx.y;
    const float* xn = x + (size_t)n * CI_ * D_;
    unsigned short* slab = xt + (size_t)n * XTROWS * 256;

    // zero pad rows (t = -1 and t = 4096), each 512B = 128 u32
    if (t0 == 0 && tid < 128)       ((unsigned int*)slab)[tid] = 0u;
    if (t0 == D_ - 32 && tid < 128) ((unsigned int*)(slab + (size_t)(XTROWS - 1) * 256))[tid] = 0u;

    const int cp_l  = tid >> 3;        // 0..31  (ci-pair within pass)
    const int t_off = (tid & 7) * 4;   // 0,4,...,28

    #pragma unroll
    for (int p = 0; p < 4; ++p) {
        const int ci0 = p * 64 + cp_l * 2;
        float4 a = *(const float4*)(xn + (size_t)ci0 * D_ + t0 + t_off);
        float4 b = *(const float4*)(xn + (size_t)(ci0 + 1) * D_ + t0 + t_off);
        const int cp = p * 32 + cp_l;
        Lp[t_off + 0][cp] = pack2(a.x, b.x);
        Lp[t_off + 1][cp] = pack2(a.y, b.y);
        Lp[t_off + 2][cp] = pack2(a.z, b.z);
        Lp[t_off + 3][cp] = pack2(a.w, b.w);
    }
    __syncthreads();

    // write: 4 iters x 8 rows; 32 lanes x 16B = one full 512B t-row
    #pragma unroll
    for (int it = 0; it < 4; ++it) {
        const int row = it * 8 + (tid >> 5);
        const int c4  = (tid & 31) * 4;           // u32 index within row
        uint4 v;
        v.x = Lp[row][c4 + 0];
        v.y = Lp[row][c4 + 1];
        v.z = Lp[row][c4 + 2];
        v.w = Lp[row][c4 + 3];
        *(uint4*)(slab + (size_t)(1 + t0 + row) * 256 + c4 * 2) = v;
    }
}

// ---------------- main: 256m x 256t 8-phase bf16 MFMA GEMM ---------------
// C[m][t] = sum_k Wt[m][k] * B[k][t]; B's 768-k column for output row t is
// the CONTIGUOUS 1536B run starting at xt slab row t (3 taps = 3 rows).
// m201-style schedule: K-tile 64, 4 quadrant-phases per K-tile, each phase
// {ds_reads || stage one 16KB half-tile} -> barrier -> lgkm(0) -> 16 MFMA
// -> barrier; stage stream +6 half-tiles ahead; ONE vmcnt(4) per K-tile.
// LDS: A[2dbuf][2mh][2kh][128r][64B] (64KB) then B likewise (64KB) = 128KB.
// Microlayout per [128r][64B] sub-tile: 16B slot XOR by (row>>1)&3
// (verified 0 bank conflicts, rounds 0-3).
__global__ __launch_bounds__(512, 2) void gemm_upfir8(
    const unsigned short* __restrict__ Wt, const unsigned short* __restrict__ xt,
    const float* __restrict__ bias, float* __restrict__ out)
{
    __shared__ __align__(16) unsigned short SL[65536];   // 128 KiB

    const int tid  = threadIdx.x;
    const int lane = tid & 63;
    const int wid  = tid >> 6;          // 0..7
    const int quad = lane >> 4;
    const int l16  = lane & 15;

    const int bt0 = blockIdx.x * 256;   // t tile
    const int bm0 = blockIdx.y * 256;   // m tile (m = co*2+phase)
    const int n   = blockIdx.z;

    // ---- staging addressing (all 8 waves stage every half-tile) ----
    const int srow = wid * 16 + (lane >> 2);            // 0..127 row in half
    const int cg   = (lane & 3) ^ ((lane >> 3) & 3);    // slot-XOR, == (srow>>1)&3 form
    const unsigned short* sA = Wt + (size_t)(bm0 + srow) * KTOT + cg * 8;
    const unsigned short* sB = xt + (size_t)n * XTROWS * 256
                                  + (size_t)(bt0 + srow) * 256 + cg * 8;

    // lds stage dests are wave-uniform (ushort offsets; bytes = 2x)
    // A(u,mh,i): (u&1)*16384 + mh*8192 + i*4096 + wid*512
    // B(u,th,i): 32768 + (u&1)*16384 + th*8192 + i*4096 + wid*512
    #define STAGE_A(u, mh) do {                                                     \
        async16(SL + (((u)&1)*16384 + (mh)*8192 + 0*4096 + wid*512),                \
                sA + (size_t)(mh)*128*KTOT + (u)*64 + 0);                           \
        async16(SL + (((u)&1)*16384 + (mh)*8192 + 1*4096 + wid*512),                \
                sA + (size_t)(mh)*128*KTOT + (u)*64 + 32); } while (0)
    #define STAGE_B(u, th) do {                                                     \
        async16(SL + (32768 + ((u)&1)*16384 + (th)*8192 + 0*4096 + wid*512),        \
                sB + (size_t)(th)*128*256 + (u)*64 + 0);                            \
        async16(SL + (32768 + ((u)&1)*16384 + (th)*8192 + 1*4096 + wid*512),        \
                sB + (size_t)(th)*128*256 + (u)*64 + 32); } while (0)

    // ---- fragment read bases (byte addresses) ----
    const int swz = quad ^ ((l16 >> 1) & 3);
    const int mh  = wid & 1;              // wave m-half
    const int wm  = mh * 128;
    const int wt  = ((wid >> 1) & 3) * 64;
    const unsigned base = (unsigned)(size_t)&SL[0];
    const unsigned aB = base + (unsigned)(mh * 16384 + l16 * 64 + swz * 16);
    const unsigned bB = base + 65536u
                      + (unsigned)(((wid >> 2) & 1) * 16384
                                   + (((wid >> 1) & 1) * 64 + l16) * 64 + swz * 16);

    facc4 acc[8][4] = {};

    // ---- prologue: stage half-tiles 0..5 (12 loads/thread) ----
    STAGE_A(0, 0); STAGE_A(0, 1); STAGE_B(0, 0); STAGE_B(0, 1);
    STAGE_A(1, 0); STAGE_A(1, 1);
    asm volatile("s_waitcnt vmcnt(4)" ::: "memory");   // K-tile 0 landed
    __builtin_amdgcn_s_barrier();

    #define MM(m, t)                                                                 \
        acc[m][t] = __builtin_amdgcn_mfma_f32_16x16x32_bf16(a[m][0], b[t][0], acc[m][t], 0, 0, 0); \
        acc[m][t] = __builtin_amdgcn_mfma_f32_16x16x32_bf16(a[m][1], b[t][1], acc[m][t], 0, 0, 0);

    #pragma unroll 2
    for (int u = 0; u < 12; ++u) {
        const unsigned au = aB + (unsigned)((u & 1) << 15);
        const unsigned bu = bB + (unsigned)((u & 1) << 15);
        frag8 a[8][2], b[4][2];

        // ---- Q0: read a[0..3][*], b[0..1][*]; stage B-lo(u+1); MFMA m0-3 x t0-1
        DSR_(a[0][0], au, "0");    DSR_(a[0][1], au, "8192");
        DSR_(a[1][0], au, "1024"); DSR_(a[1][1], au, "9216");
        DSR_(a[2][0], au, "2048"); DSR_(a[2][1], au, "10240");
        DSR_(a[3][0], au, "3072"); DSR_(a[3][1], au, "11264");
        DSR_(b[0][0], bu, "0");    DSR_(b[0][1], bu, "8192");
        DSR_(b[1][0], bu, "1024"); DSR_(b[1][1], bu, "9216");
        if (u < 11) STAGE_B(u + 1, 0);
        __builtin_amdgcn_s_barrier();
        asm volatile("s_waitcnt lgkmcnt(0)" ::: "memory");
        __builtin_amdgcn_sched_barrier(0);
        __builtin_amdgcn_s_setprio(1);
        MM(0, 0) MM(1, 0) MM(2, 0) MM(3, 0)
        MM(0, 1) MM(1, 1) MM(2, 1) MM(3, 1)
        __builtin_amdgcn_s_setprio(0);
        __builtin_amdgcn_s_barrier();

        // ---- Q1: read a[4..7][*]; stage B-hi(u+1); MFMA m4-7 x t0-1
        DSR_(a[4][0], au, "4096"); DSR_(a[4][1], au, "12288");
        DSR_(a[5][0], au, "5120"); DSR_(a[5][1], au, "13312");
        DSR_(a[6][0], au, "6144"); DSR_(a[6][1], au, "14336");
        DSR_(a[7][0], au, "7168"); DSR_(a[7][1], au, "15360");
        if (u < 11) STAGE_B(u + 1, 1);
        __builtin_amdgcn_s_barrier();
        asm volatile("s_waitcnt lgkmcnt(0)" ::: "memory");
        __builtin_amdgcn_sched_barrier(0);
        __builtin_amdgcn_s_setprio(1);
        MM(4, 0) MM(5, 0) MM(6, 0) MM(7, 0)
        MM(4, 1) MM(5, 1) MM(6, 1) MM(7, 1)
        __builtin_amdgcn_s_setprio(0);
        __builtin_amdgcn_s_barrier();

        // ---- Q2: read b[2..3][*]; stage A-lo(u+2); MFMA m4-7 x t2-3
        DSR_(b[2][0], bu, "2048"); DSR_(b[2][1], bu, "10240");
        DSR_(b[3][0], bu, "3072"); DSR_(b[3][1], bu, "11264");
        if (u < 10) STAGE_A(u + 2, 0);
        __builtin_amdgcn_s_barrier();
        asm volatile("s_waitcnt lgkmcnt(0)" ::: "memory");
        __builtin_amdgcn_sched_barrier(0);
        __builtin_amdgcn_s_setprio(1);
        MM(4, 2) MM(5, 2) MM(6, 2) MM(7, 2)
        MM(4, 3) MM(5, 3) MM(6, 3) MM(7, 3)
        __builtin_amdgcn_s_setprio(0);
        __builtin_amdgcn_s_barrier();

        // ---- Q3: no reads; stage A-hi(u+2); MFMA m0-3 x t2-3; vmcnt gate
        if (u < 10) STAGE_A(u + 2, 1);
        __builtin_amdgcn_s_barrier();
        __builtin_amdgcn_sched_barrier(0);
        __builtin_amdgcn_s_setprio(1);
        MM(0, 2) MM(1, 2) MM(2, 2) MM(3, 2)
        MM(0, 3) MM(1, 3) MM(2, 3) MM(3, 3)
        __builtin_amdgcn_s_setprio(0);
        if (u < 10) { asm volatile("s_waitcnt vmcnt(4)" ::: "memory"); }
        else        { asm volatile("s_waitcnt vmcnt(0)" ::: "memory"); }
        __builtin_amdgcn_s_barrier();
    }
    #undef MM
    #undef STAGE_A
    #undef STAGE_B

    // epilogue: D row = quad*4+reg (= m), col = l16 (= t); regs span 2 co x 2 phase
    #pragma unroll
    for (int m8 = 0; m8 < 8; ++m8) {
        int m0  = bm0 + wm + m8 * 16 + quad * 4;
        int co0 = m0 >> 1;
        float b0 = bias[co0];
        float b1 = bias[co0 + 1];
        #pragma unroll
        for (int t4 = 0; t4 < 4; ++t4) {
            int t = bt0 + wt + t4 * 16 + l16;
            facc4 v = acc[m8][t4];
            float* p0 = out + ((size_t)(n * CO_ + co0)) * DO_ + 2 * t;
            float* p1 = p0 + DO_;
            *(float2*)p0 = make_float2(v.x + b0, v.y + b0);
            *(float2*)p1 = make_float2(v.z + b1, v.w + b1);
        }
    }
}

// ---------------- fallback (round-1 verified kernel) ---------------------
__global__ __launch_bounds__(256) void upconv_fir_f32(
    const float* __restrict__ x, const float* __restrict__ w,
    const float* __restrict__ bias, float* __restrict__ out)
{
    __shared__ float ws[CI_][4];
    const int tid = threadIdx.x;
    const int co  = blockIdx.y;
    const int n   = blockIdx.z;
    {
        const float* wc = w + (size_t)co * CI_ * 3;
        ws[tid][0] = wc[tid * 3 + 0];
        ws[tid][1] = wc[tid * 3 + 1];
        ws[tid][2] = wc[tid * 3 + 2];
        ws[tid][3] = 0.f;
    }
    __syncthreads();
    const int t0 = (blockIdx.x * 256 + tid) * 8;
    const float* xn = x + (size_t)n * CI_ * D_;
    float s[10], g[9];
    #pragma unroll
    for (int k = 0; k < 10; ++k) s[k] = 0.f;
    #pragma unroll
    for (int k = 0; k < 9; ++k) g[k] = 0.f;
    #pragma unroll 2
    for (int ci = 0; ci < CI_; ++ci) {
        const float* xr = xn + ci * D_;
        float4 va = *(const float4*)(xr + t0);
        float4 vb = *(const float4*)(xr + t0 + 4);
        float  xm = (t0 > 0)      ? xr[t0 - 1] : 0.f;
        float  xp = (t0 + 8 < D_) ? xr[t0 + 8] : 0.f;
        float4 wv = *(const float4*)(&ws[ci][0]);
        const float w0 = wv.x, w1 = wv.y, w2 = wv.z;
        float xa[10];
        xa[0] = xm; xa[1] = va.x; xa[2] = va.y; xa[3] = va.z; xa[4] = va.w;
        xa[5] = vb.x; xa[6] = vb.y; xa[7] = vb.z; xa[8] = vb.w; xa[9] = xp;
        #pragma unroll
        for (int k = 0; k < 10; ++k) s[k] += w1 * xa[k];
        #pragma unroll
        for (int k = 0; k < 9; ++k)  g[k] += w0 * xa[k] + w2 * xa[k + 1];
    }
    const float b = bias[co];
    float o16[16];
    #pragma unroll
    for (int tt = 0; tt < 8; ++tt) {
        o16[2 * tt]     = 0.25f * (s[tt] + g[tt + 1]) + 0.75f * (g[tt] + s[tt + 1]) + b;
        o16[2 * tt + 1] = 0.25f * (g[tt] + s[tt + 2]) + 0.75f * (s[tt + 1] + g[tt + 1]) + b;
    }
    float* ob = out + ((size_t)n * CO_ + co) * DO_ + 2 * t0;
    *(float4*)(ob + 0)  = make_float4(o16[0],  o16[1],  o16[2],  o16[3]);
    *(float4*)(ob + 4)  = make_float4(o16[4],  o16[5],  o16[6],  o16[7]);
    *(float4*)(ob + 8)  = make_float4(o16[8],  o16[9],  o16[10], o16[11]);
    *(float4*)(ob + 12) = make_float4(o16[12], o16[13], o16[14], o16[15]);
}

extern "C" void kernel_launch(void* const* d_in, const int* in_sizes, int n_in,
                              void* d_out, int out_size, void* d_ws, size_t ws_size,
                              hipStream_t stream) {
    const float* x  = (const float*)d_in[0];
    const float* w  = (const float*)d_in[1];
    const float* b  = (const float*)d_in[2];
    float* out      = (float*)d_out;

    const size_t need = (size_t)WT_ELEMS * 2 + XT_ELEMS * 2;
    if (ws_size >= need) {
        unsigned short* Wt = (unsigned short*)d_ws;
        unsigned short* xt = Wt + WT_ELEMS;
        prep_wt<<<dim3(CO_), 256, 0, stream>>>(w, Wt);
        prep_xt2<<<dim3(D_ / 32, N_), 256, 0, stream>>>(x, xt);
        gemm_upfir8<<<dim3(D_ / 256, 2, N_), 512, 0, stream>>>(Wt, xt, b, out);
    } else {
        upconv_fir_f32<<<dim3(2, CO_, N_), 256, 0, stream>>>(x, w, b, out);
    }
}